// Round 1
// baseline (1681.234 us; speedup 1.0000x reference)
//
#include <hip/hip_runtime.h>
#include <hip/hip_bf16.h>

// ---------------------------------------------------------------------------
// JAX threefry2x32 replication.
// jax.random.key(42) -> key data (0, 42).
// Toggle: modern JAX (>=0.4.30) defaults jax_threefry_partitionable=True.
//   partitionable: random_bits[i] = o0^o1 of TF(key, hi=0, lo=i);
//                  split(key)[i] = TF(key, 0, i) (fold-like, both words).
//   original:      random_bits over n elems: blocks (c, c+n/2), word0 for
//                  first half, word1 for second; split uses iota(2*num).
// For p=0.5 bernoulli: keep  <=>  bits < 2^31 (sign bit clear).
// ---------------------------------------------------------------------------
#define JAX_THREEFRY_PARTITIONABLE 1

__host__ __device__ __forceinline__ unsigned rotl32(unsigned x, int d) {
  return (x << d) | (x >> (32 - d));
}

__host__ __device__ __forceinline__ void threefry2x32(
    unsigned k0, unsigned k1, unsigned x0, unsigned x1,
    unsigned& o0, unsigned& o1) {
  unsigned ks2 = k0 ^ k1 ^ 0x1BD11BDAu;
  unsigned v0 = x0 + k0, v1 = x1 + k1;
#define TF_R(r) { v0 += v1; v1 = rotl32(v1, (r)); v1 ^= v0; }
  TF_R(13) TF_R(15) TF_R(26) TF_R(6)  v0 += k1;  v1 += ks2 + 1u;
  TF_R(17) TF_R(29) TF_R(16) TF_R(24) v0 += ks2; v1 += k0 + 2u;
  TF_R(13) TF_R(15) TF_R(26) TF_R(6)  v0 += k0;  v1 += k1 + 3u;
  TF_R(17) TF_R(29) TF_R(16) TF_R(24) v0 += k1;  v1 += ks2 + 4u;
  TF_R(13) TF_R(15) TF_R(26) TF_R(6)  v0 += ks2; v1 += k0 + 5u;
#undef TF_R
  o0 = v0; o1 = v1;
}

// scale = 2.0 if kept else 0.0; pos = flat index in the dropout'ed array,
// n = total element count of that array (used only in original mode).
__device__ __forceinline__ float drop_scale(unsigned ka, unsigned kb,
                                            unsigned pos, unsigned n) {
#if JAX_THREEFRY_PARTITIONABLE
  (void)n;
  unsigned o0, o1;
  threefry2x32(ka, kb, 0u, pos, o0, o1);
  return ((o0 ^ o1) >> 31) ? 0.0f : 2.0f;
#else
  unsigned h = n >> 1;
  unsigned c = (pos < h) ? pos : pos - h;
  unsigned o0, o1;
  threefry2x32(ka, kb, c, c + h, o0, o1);
  unsigned bits = (pos < h) ? o0 : o1;
  return (bits >> 31) ? 0.0f : 2.0f;
#endif
}

__device__ __forceinline__ void atomAddF(float* p, float v) {
  unsafeAtomicAdd(p, v);  // global_atomic_add_f32 on gfx950
}

// ---------------------------------------------------------------------------
// Kernels
// ---------------------------------------------------------------------------

__global__ __launch_bounds__(256) void k_deg(const int* __restrict__ dst,
                                             float* __restrict__ deg, int E) {
  int e = blockIdx.x * 256 + threadIdx.x;
  if (e < E) atomAddF(&deg[dst[e]], 1.0f);
}

// sum[dst[e], j] += dropout(features[sel[src[e]], j]) * 2 ; d = 128
__global__ __launch_bounds__(256) void k_agg_feat(
    const float* __restrict__ feats, const int* __restrict__ sel,
    const int* __restrict__ src, const int* __restrict__ dst,
    float* __restrict__ sum, long n_elems,
    unsigned ka, unsigned kb, unsigned nmask) {
  long tid = (long)blockIdx.x * 256 + threadIdx.x;
  if (tid >= n_elems) return;
  int e = (int)(tid >> 7);
  int j = (int)(tid & 127);
  int r = src[e];                       // row in feat_src [Nsrc,128]
  float v = feats[(size_t)sel[r] * 128 + j];
  v *= drop_scale(ka, kb, (unsigned)r * 128u + (unsigned)j, nmask);
  atomAddF(&sum[(size_t)dst[e] * 128 + j], v);
}

// a = relu(sum/deg + dropout(features[sel[i]])) ; in-place on sum ; d = 128
__global__ __launch_bounds__(256) void k_finish128(
    const float* __restrict__ feats, const int* __restrict__ sel,
    const float* __restrict__ deg, float* __restrict__ a, long n_elems,
    unsigned ka, unsigned kb, unsigned nmask) {
  long tid = (long)blockIdx.x * 256 + threadIdx.x;
  if (tid >= n_elems) return;
  int i = (int)(tid >> 7);
  int j = (int)(tid & 127);
  float d = deg[i];
  float neigh = (d > 0.0f) ? a[tid] / d : 0.0f;
  float hs = feats[(size_t)sel[i] * 128 + j] *
             drop_scale(ka, kb, (unsigned)tid, nmask);
  float v = neigh + hs;
  a[tid] = v > 0.0f ? v : 0.0f;
}

// sum[dst[e], j] += dropout(X[src[e], j]) * 2 ; d = 256, no sel indirection
__global__ __launch_bounds__(256) void k_agg_dense256(
    const float* __restrict__ X, const int* __restrict__ src,
    const int* __restrict__ dst, float* __restrict__ sum, long n_elems,
    unsigned ka, unsigned kb, unsigned nmask) {
  long tid = (long)blockIdx.x * 256 + threadIdx.x;
  if (tid >= n_elems) return;
  int e = (int)(tid >> 8);
  int j = (int)(tid & 255);
  int r = src[e];
  unsigned pos = (unsigned)r * 256u + (unsigned)j;
  float v = X[(size_t)r * 256 + j] * drop_scale(ka, kb, pos, nmask);
  atomAddF(&sum[(size_t)dst[e] * 256 + j], v);
}

// a = relu(sum/deg + dropout(hself)) ; in-place on sum ; d = 256
__global__ __launch_bounds__(256) void k_finish256(
    const float* __restrict__ hself, const float* __restrict__ deg,
    float* __restrict__ a, long n_elems,
    unsigned ka, unsigned kb, unsigned nmask) {
  long tid = (long)blockIdx.x * 256 + threadIdx.x;
  if (tid >= n_elems) return;
  int i = (int)(tid >> 8);
  float d = deg[i];
  float neigh = (d > 0.0f) ? a[tid] / d : 0.0f;
  float hs = hself[tid] * drop_scale(ka, kb, (unsigned)tid, nmask);
  float v = neigh + hs;
  a[tid] = v > 0.0f ? v : 0.0f;
}

// C[M,256] = A[M,128] @ W[128,256] + bias. grid = (ceil(M/128), 2).
// 128x128 tile, BK=64, 256 threads, 8x8 micro-tile.
__global__ __launch_bounds__(256) void k_gemm_k128(
    const float* __restrict__ A, const float* __restrict__ W,
    const float* __restrict__ bias, float* __restrict__ C, int M) {
  __shared__ float As[64 * 128];  // As[k][r]  (transposed)
  __shared__ float Ws[64 * 128];  // Ws[k][n]
  const int r0 = blockIdx.x * 128;
  const int n0 = blockIdx.y * 128;
  const int t = threadIdx.x;
  const int tx = t & 15, ty = t >> 4;
  float acc[8][8] = {};
  for (int kt = 0; kt < 128; kt += 64) {
    // stage W rows kt..kt+63, cols n0..n0+127
    {
      const float4* Wv = (const float4*)W;   // 64 float4 per W row
      float4* Wsv = (float4*)Ws;
      for (int i = t; i < 64 * 32; i += 256) {
        int k = i >> 5, c4 = i & 31;
        Wsv[k * 32 + c4] = Wv[(size_t)(kt + k) * 64 + (n0 >> 2) + c4];
      }
    }
    // stage A rows r0..r0+127, cols kt..kt+63, transposed into As[k][r]
    for (int i = t; i < 128 * 16; i += 256) {
      int r = i >> 4, c4 = i & 15;
      int gr = r0 + r;
      float4 v = make_float4(0.f, 0.f, 0.f, 0.f);
      if (gr < M) v = ((const float4*)A)[(size_t)gr * 32 + (kt >> 2) + c4];
      int k = c4 * 4;
      As[(k + 0) * 128 + r] = v.x;
      As[(k + 1) * 128 + r] = v.y;
      As[(k + 2) * 128 + r] = v.z;
      As[(k + 3) * 128 + r] = v.w;
    }
    __syncthreads();
#pragma unroll 4
    for (int k = 0; k < 64; ++k) {
      const float4 a0 = *(const float4*)&As[k * 128 + ty * 8];
      const float4 a1 = *(const float4*)&As[k * 128 + ty * 8 + 4];
      const float4 w0 = *(const float4*)&Ws[k * 128 + tx * 8];
      const float4 w1 = *(const float4*)&Ws[k * 128 + tx * 8 + 4];
      const float av[8] = {a0.x, a0.y, a0.z, a0.w, a1.x, a1.y, a1.z, a1.w};
      const float wv[8] = {w0.x, w0.y, w0.z, w0.w, w1.x, w1.y, w1.z, w1.w};
#pragma unroll
      for (int i = 0; i < 8; ++i)
#pragma unroll
        for (int j = 0; j < 8; ++j)
          acc[i][j] = fmaf(av[i], wv[j], acc[i][j]);
    }
    __syncthreads();
  }
  float bj[8];
#pragma unroll
  for (int j = 0; j < 8; ++j) bj[j] = bias[n0 + tx * 8 + j];
#pragma unroll
  for (int i = 0; i < 8; ++i) {
    int r = r0 + ty * 8 + i;
    if (r < M) {
      float4 c0 = make_float4(acc[i][0] + bj[0], acc[i][1] + bj[1],
                              acc[i][2] + bj[2], acc[i][3] + bj[3]);
      float4 c1 = make_float4(acc[i][4] + bj[4], acc[i][5] + bj[5],
                              acc[i][6] + bj[6], acc[i][7] + bj[7]);
      *(float4*)&C[(size_t)r * 256 + n0 + tx * 8] = c0;
      *(float4*)&C[(size_t)r * 256 + n0 + tx * 8 + 4] = c1;
    }
  }
}

// C[M,47] = A[M,256] @ W[256,47] + bias ; 32 rows per block.
__global__ __launch_bounds__(256) void k_gemm_out(
    const float* __restrict__ A, const float* __restrict__ W,
    const float* __restrict__ bias, float* __restrict__ C, int M) {
  __shared__ float Ws[256 * 47];
  __shared__ float As[32 * 256];
  const int t = threadIdx.x;
  for (int i = t; i < 256 * 47; i += 256) Ws[i] = W[i];
  const int r0 = blockIdx.x * 32;
  for (int i = t; i < 32 * 256; i += 256) {
    int r = r0 + (i >> 8);
    As[i] = (r < M) ? A[(size_t)r * 256 + (i & 255)] : 0.f;
  }
  __syncthreads();
  for (int o = t; o < 32 * 47; o += 256) {
    int r = o / 47, n = o - r * 47;
    if (r0 + r >= M) continue;
    float acc = bias[n];
#pragma unroll 8
    for (int k = 0; k < 256; ++k)
      acc = fmaf(As[r * 256 + k], Ws[k * 47 + n], acc);
    C[(size_t)(r0 + r) * 47 + n] = acc;
  }
}

// ---------------------------------------------------------------------------
// Launch
// ---------------------------------------------------------------------------
extern "C" void kernel_launch(void* const* d_in, const int* in_sizes, int n_in,
                              void* d_out, int out_size, void* d_ws,
                              size_t ws_size, hipStream_t stream) {
  const float* features = (const float*)d_in[0];
  const int* s0   = (const int*)d_in[1];
  const int* s1   = (const int*)d_in[2];
  const int* s2   = (const int*)d_in[3];
  const int* src0 = (const int*)d_in[4];
  const int* dst0 = (const int*)d_in[5];
  const int* src1 = (const int*)d_in[6];
  const int* dst1 = (const int*)d_in[7];
  const float* W1 = (const float*)d_in[8];
  const float* b1 = (const float*)d_in[9];
  const float* W2 = (const float*)d_in[10];
  const float* b2 = (const float*)d_in[11];
  float* out = (float*)d_out;

  const int N0 = in_sizes[1], N1 = in_sizes[2];
  const int E0 = in_sizes[4], E1 = in_sizes[6];

  // ---- key derivation (host, deterministic; matches jax.random.key(42)) ----
  unsigned dk[3][2], kfs[3][2], khs[3][2];
#if JAX_THREEFRY_PARTITIONABLE
  for (int i = 0; i < 3; ++i)
    threefry2x32(0u, 42u, 0u, (unsigned)i, dk[i][0], dk[i][1]);
  for (int i = 0; i < 3; ++i) {
    threefry2x32(dk[i][0], dk[i][1], 0u, 0u, kfs[i][0], kfs[i][1]);  // k1: feat_src
    threefry2x32(dk[i][0], dk[i][1], 0u, 1u, khs[i][0], khs[i][1]);  // k2: h_self
  }
#else
  {
    unsigned a0, b0, a1, b1_, a2, b2_;
    threefry2x32(0u, 42u, 0u, 3u, a0, b0);
    threefry2x32(0u, 42u, 1u, 4u, a1, b1_);
    threefry2x32(0u, 42u, 2u, 5u, a2, b2_);
    dk[0][0] = a0;  dk[0][1] = a1;
    dk[1][0] = a2;  dk[1][1] = b0;
    dk[2][0] = b1_; dk[2][1] = b2_;
  }
  for (int i = 0; i < 3; ++i) {
    unsigned p0, q0, p1, q1;
    threefry2x32(dk[i][0], dk[i][1], 0u, 2u, p0, q0);
    threefry2x32(dk[i][0], dk[i][1], 1u, 3u, p1, q1);
    kfs[i][0] = p0; kfs[i][1] = p1;
    khs[i][0] = q0; khs[i][1] = q1;
  }
#endif

  // ---- workspace layout (floats) ----
  float* p = (float*)d_ws;
  float* sum1 = p; p += (size_t)N1 * 128;   // 51.2 MB, becomes a1 in place
  float* n1v  = p; p += (size_t)N1 * 256;   // 102.4 MB
  float* sum0 = p; p += (size_t)N0 * 128;   // 5.1 MB, becomes a0
  float* n0v  = p; p += (size_t)N0 * 256;   // 10.2 MB
  float* sum2 = p; p += (size_t)N0 * 256;   // 10.2 MB, becomes a
  float* deg1 = p; p += N1;
  float* deg0 = p; p += N0;

  hipMemsetAsync(sum1, 0, (size_t)N1 * 128 * 4, stream);
  hipMemsetAsync(sum0, 0, (size_t)N0 * 128 * 4, stream);
  hipMemsetAsync(sum2, 0, (size_t)N0 * 256 * 4, stream);
  hipMemsetAsync(deg1, 0, (size_t)N1 * 4, stream);
  hipMemsetAsync(deg0, 0, (size_t)N0 * 4, stream);

  k_deg<<<(E1 + 255) / 256, 256, 0, stream>>>(dst1, deg1, E1);
  k_deg<<<(E0 + 255) / 256, 256, 0, stream>>>(dst0, deg0, E0);

  // ---- layer 0, hop 1: a1 = agg(src1,dst1, h2, h1), n1 = a1@W1+b1 ----
  {
    long T = (long)E1 * 128;
    k_agg_feat<<<(int)((T + 255) / 256), 256, 0, stream>>>(
        features, s2, src1, dst1, sum1, T, kfs[1][0], kfs[1][1],
        (unsigned)((size_t)in_sizes[3] * 128));
    long Tf = (long)N1 * 128;
    k_finish128<<<(int)((Tf + 255) / 256), 256, 0, stream>>>(
        features, s1, deg1, sum1, Tf, khs[1][0], khs[1][1],
        (unsigned)((size_t)N1 * 128));
    dim3 g((N1 + 127) / 128, 2);
    k_gemm_k128<<<g, 256, 0, stream>>>(sum1, W1, b1, n1v, N1);
  }

  // ---- layer 0, hop 0: a0 = agg(src0,dst0, h1, h0), n0 = a0@W1+b1 ----
  {
    long T = (long)E0 * 128;
    k_agg_feat<<<(int)((T + 255) / 256), 256, 0, stream>>>(
        features, s1, src0, dst0, sum0, T, kfs[0][0], kfs[0][1],
        (unsigned)((size_t)N1 * 128));
    long Tf = (long)N0 * 128;
    k_finish128<<<(int)((Tf + 255) / 256), 256, 0, stream>>>(
        features, s0, deg0, sum0, Tf, khs[0][0], khs[0][1],
        (unsigned)((size_t)N0 * 128));
    dim3 g((N0 + 127) / 128, 2);
    k_gemm_k128<<<g, 256, 0, stream>>>(sum0, W1, b1, n0v, N0);
  }

  // ---- layer 1: a = agg(src0,dst0, n1, n0), out = a@W2+b2 ----
  {
    long T = (long)E0 * 256;
    k_agg_dense256<<<(int)((T + 255) / 256), 256, 0, stream>>>(
        n1v, src0, dst0, sum2, T, kfs[2][0], kfs[2][1],
        (unsigned)((size_t)N1 * 256));
    long Tf = (long)N0 * 256;
    k_finish256<<<(int)((Tf + 255) / 256), 256, 0, stream>>>(
        n0v, deg0, sum2, Tf, khs[2][0], khs[2][1],
        (unsigned)((size_t)N0 * 256));
    k_gemm_out<<<(N0 + 31) / 32, 256, 0, stream>>>(sum2, W2, b2, out, N0);
  }
}

// Round 2
// 1246.153 us; speedup vs baseline: 1.3491x; 1.3491x over previous
//
#include <hip/hip_runtime.h>
#include <hip/hip_bf16.h>

// ---------------------------------------------------------------------------
// JAX threefry2x32 replication (partitionable mode verified in round 1).
// keep  <=>  (o0^o1) < 2^31   for p = 0.5.
// ---------------------------------------------------------------------------
__host__ __device__ __forceinline__ unsigned rotl32(unsigned x, int d) {
  return (x << d) | (x >> (32 - d));
}

__host__ __device__ __forceinline__ void threefry2x32(
    unsigned k0, unsigned k1, unsigned x0, unsigned x1,
    unsigned& o0, unsigned& o1) {
  unsigned ks2 = k0 ^ k1 ^ 0x1BD11BDAu;
  unsigned v0 = x0 + k0, v1 = x1 + k1;
#define TF_R(r) { v0 += v1; v1 = rotl32(v1, (r)); v1 ^= v0; }
  TF_R(13) TF_R(15) TF_R(26) TF_R(6)  v0 += k1;  v1 += ks2 + 1u;
  TF_R(17) TF_R(29) TF_R(16) TF_R(24) v0 += ks2; v1 += k0 + 2u;
  TF_R(13) TF_R(15) TF_R(26) TF_R(6)  v0 += k0;  v1 += k1 + 3u;
  TF_R(17) TF_R(29) TF_R(16) TF_R(24) v0 += k1;  v1 += ks2 + 4u;
  TF_R(13) TF_R(15) TF_R(26) TF_R(6)  v0 += ks2; v1 += k0 + 5u;
#undef TF_R
  o0 = v0; o1 = v1;
}

__device__ __forceinline__ float drop_scale(unsigned ka, unsigned kb,
                                            unsigned pos) {
  unsigned o0, o1;
  threefry2x32(ka, kb, 0u, pos, o0, o1);
  return ((o0 ^ o1) >> 31) ? 0.0f : 2.0f;
}

__device__ __forceinline__ float bf2f(unsigned short u) {
  unsigned x = ((unsigned)u) << 16;
  float f;
  __builtin_memcpy(&f, &x, 4);
  return f;
}
__device__ __forceinline__ unsigned short f2bf(float f) {
  __hip_bfloat16 h = __float2bfloat16(f);
  unsigned short u;
  __builtin_memcpy(&u, &h, 2);
  return u;
}

// ---------------------------------------------------------------------------
// CSR build: count, 3-kernel exclusive scan, fill
// ---------------------------------------------------------------------------
__global__ __launch_bounds__(256) void k_count(const int* __restrict__ dst,
                                               int* __restrict__ deg, int E) {
  int e = blockIdx.x * 256 + threadIdx.x;
  if (e < E) atomicAdd(&deg[dst[e]], 1);
}

// exclusive scan pass 1: per-1024 chunk; o[i] = excl prefix within chunk
__global__ __launch_bounds__(256) void k_scan1(const int* __restrict__ d,
                                               int* __restrict__ o,
                                               int* __restrict__ bsum, int n) {
  __shared__ int ls[256];
  int t = threadIdx.x;
  int base = blockIdx.x * 1024 + t * 4;
  int v[4], s = 0;
#pragma unroll
  for (int q = 0; q < 4; ++q) {
    int i = base + q;
    v[q] = (i < n) ? d[i] : 0;
    s += v[q];
  }
  ls[t] = s;
  __syncthreads();
  for (int off = 1; off < 256; off <<= 1) {
    int x = (t >= off) ? ls[t - off] : 0;
    __syncthreads();
    ls[t] += x;
    __syncthreads();
  }
  int run = ls[t] - s;
  if (t == 255) bsum[blockIdx.x] = ls[255];
#pragma unroll
  for (int q = 0; q < 4; ++q) {
    int i = base + q;
    if (i < n) o[i] = run;
    run += v[q];
  }
}

// pass 3: add scanned block sums
__global__ __launch_bounds__(256) void k_scan3(int* __restrict__ o,
                                               const int* __restrict__ bx,
                                               int n) {
  int t = threadIdx.x;
  int add = bx[blockIdx.x];
  int base = blockIdx.x * 1024 + t * 4;
#pragma unroll
  for (int q = 0; q < 4; ++q) {
    int i = base + q;
    if (i < n) o[i] += add;
  }
}

// fill: csr_r[pos] = src[e]; csr_g[pos] = sel[src[e]]
__global__ __launch_bounds__(256) void k_fill(
    const int* __restrict__ src, const int* __restrict__ dst,
    const int* __restrict__ sel, const int* __restrict__ off,
    int* __restrict__ cur, int* __restrict__ csr_r, int* __restrict__ csr_g,
    int E) {
  int e = blockIdx.x * 256 + threadIdx.x;
  if (e >= E) return;
  int d = dst[e];
  int pos = off[d] + atomicAdd(&cur[d], 1);
  int r = src[e];
  csr_r[pos] = r;
  csr_g[pos] = sel[r];
}

// ---------------------------------------------------------------------------
// Aggregation d=128: one wave per dst node. lane owns cols {2l, 2l+1}.
// out (bf16) = relu( mean_e dropout(feats[g_e]) + dropout(feats[sel_self[i]]) )
// ---------------------------------------------------------------------------
__global__ __launch_bounds__(256) void k_agg128(
    const float* __restrict__ feats, const int* __restrict__ off,
    const int* __restrict__ csr_r, const int* __restrict__ csr_g,
    const int* __restrict__ sel_self, unsigned short* __restrict__ outbf,
    int N, unsigned kfa, unsigned kfb, unsigned kha, unsigned khb) {
  int wave = (blockIdx.x * 256 + threadIdx.x) >> 6;
  int lane = threadIdx.x & 63;
  if (wave >= N) return;
  int beg = off[wave], end = off[wave + 1];
  float acc0 = 0.f, acc1 = 0.f;
  for (int base = beg; base < end; base += 64) {
    int idx = base + lane;
    int r_l = 0, g_l = 0;
    if (idx < end) { r_l = csr_r[idx]; g_l = csr_g[idx]; }
    int cnt = min(64, end - base);
    for (int b = 0; b < cnt; ++b) {
      int r = __shfl(r_l, b), g = __shfl(g_l, b);
      float2 f = *(const float2*)(feats + (size_t)g * 128 + lane * 2);
      unsigned p = (unsigned)r * 128u + (unsigned)(lane * 2);
      acc0 += f.x * drop_scale(kfa, kfb, p);
      acc1 += f.y * drop_scale(kfa, kfb, p + 1);
    }
  }
  float deg = (float)(end - beg);
  float inv = deg > 0.f ? 1.0f / deg : 0.f;
  float n0 = acc0 * inv, n1 = acc1 * inv;
  float2 sf = *(const float2*)(feats + (size_t)sel_self[wave] * 128 + lane * 2);
  unsigned ps = (unsigned)wave * 128u + (unsigned)(lane * 2);
  float v0 = n0 + sf.x * drop_scale(kha, khb, ps);
  float v1 = n1 + sf.y * drop_scale(kha, khb, ps + 1);
  v0 = v0 > 0.f ? v0 : 0.f;
  v1 = v1 > 0.f ? v1 : 0.f;
  ushort2 u;
  u.x = f2bf(v0);
  u.y = f2bf(v1);
  *(ushort2*)(outbf + (size_t)wave * 128 + lane * 2) = u;
}

// ---------------------------------------------------------------------------
// Aggregation d=256 over bf16 rows: one wave per dst. lane owns cols 4l..4l+3.
// ---------------------------------------------------------------------------
__global__ __launch_bounds__(256) void k_agg256(
    const unsigned short* __restrict__ X, const int* __restrict__ off,
    const int* __restrict__ csr_r, const unsigned short* __restrict__ self,
    unsigned short* __restrict__ outbf, int N,
    unsigned kfa, unsigned kfb, unsigned kha, unsigned khb) {
  int wave = (blockIdx.x * 256 + threadIdx.x) >> 6;
  int lane = threadIdx.x & 63;
  if (wave >= N) return;
  int beg = off[wave], end = off[wave + 1];
  float acc[4] = {0.f, 0.f, 0.f, 0.f};
  for (int base = beg; base < end; base += 64) {
    int idx = base + lane;
    int r_l = 0;
    if (idx < end) r_l = csr_r[idx];
    int cnt = min(64, end - base);
    for (int b = 0; b < cnt; ++b) {
      int r = __shfl(r_l, b);
      ushort4 raw = ((const ushort4*)(X + (size_t)r * 256))[lane];
      unsigned p = (unsigned)r * 256u + (unsigned)(lane * 4);
      acc[0] += bf2f(raw.x) * drop_scale(kfa, kfb, p);
      acc[1] += bf2f(raw.y) * drop_scale(kfa, kfb, p + 1);
      acc[2] += bf2f(raw.z) * drop_scale(kfa, kfb, p + 2);
      acc[3] += bf2f(raw.w) * drop_scale(kfa, kfb, p + 3);
    }
  }
  float deg = (float)(end - beg);
  float inv = deg > 0.f ? 1.0f / deg : 0.f;
  ushort4 sr = ((const ushort4*)(self + (size_t)wave * 256))[lane];
  unsigned ps = (unsigned)wave * 256u + (unsigned)(lane * 4);
  float sv[4] = {bf2f(sr.x), bf2f(sr.y), bf2f(sr.z), bf2f(sr.w)};
  ushort4 u;
  unsigned short* up = (unsigned short*)&u;
#pragma unroll
  for (int c = 0; c < 4; ++c) {
    float v = acc[c] * inv + sv[c] * drop_scale(kha, khb, ps + c);
    up[c] = f2bf(v > 0.f ? v : 0.f);
  }
  ((ushort4*)(outbf + (size_t)wave * 256))[lane] = u;
}

// ---------------------------------------------------------------------------
// W1 transpose+convert: W1T[n*128+k] = bf16(W1[k*256+n])
// ---------------------------------------------------------------------------
__global__ __launch_bounds__(256) void k_prepW(const float* __restrict__ W1,
                                               unsigned short* __restrict__ W1T) {
  int tid = blockIdx.x * 256 + threadIdx.x;  // 32768
  int n = tid >> 7, k = tid & 127;
  W1T[n * 128 + k] = f2bf(W1[k * 256 + n]);
}

// ---------------------------------------------------------------------------
// GEMM1: C[M,256](bf16) = A[M,128](bf16) @ W1 + b1, via MFMA 16x16x32 bf16.
// grid (ceil(M/128), 2). Block 256 = 4 waves, each wave a 64x64 C sub-tile.
// LDS: As/Bs 128 rows x 72 (64 k + 8 pad) bf16, K staged in 2 passes of 64.
// ---------------------------------------------------------------------------
typedef short v8s __attribute__((ext_vector_type(8)));
typedef float v4f __attribute__((ext_vector_type(4)));

__global__ __launch_bounds__(256) void k_gemm1(
    const unsigned short* __restrict__ A, const unsigned short* __restrict__ W1T,
    const float* __restrict__ bias, unsigned short* __restrict__ C, int M) {
  __shared__ unsigned short As[128 * 72];
  __shared__ unsigned short Bs[128 * 72];
  const int t = threadIdx.x;
  const int r0 = blockIdx.x * 128, n0 = blockIdx.y * 128;
  const int wv = t >> 6, lane = t & 63;
  const int mb = (wv >> 1) * 64, nb = (wv & 1) * 64;
  const int qm = lane & 15, quad = lane >> 4;
  v4f acc[4][4];
#pragma unroll
  for (int i = 0; i < 4; ++i)
#pragma unroll
    for (int j = 0; j < 4; ++j) acc[i][j] = (v4f){0.f, 0.f, 0.f, 0.f};

  for (int kt = 0; kt < 128; kt += 64) {
    // stage A rows r0..r0+127, k kt..kt+63  (8 chunks of 8 bf16 per row)
#pragma unroll
    for (int it = 0; it < 4; ++it) {
      int i = t + it * 256;            // 0..1023
      int r = i >> 3, c = i & 7;
      uint4 v = make_uint4(0, 0, 0, 0);
      int gr = r0 + r;
      if (gr < M) v = ((const uint4*)A)[(size_t)gr * 16 + (kt >> 3) + c];
      *(uint4*)&As[r * 72 + c * 8] = v;
    }
#pragma unroll
    for (int it = 0; it < 4; ++it) {
      int i = t + it * 256;
      int n = i >> 3, c = i & 7;
      uint4 v = ((const uint4*)W1T)[(size_t)(n0 + n) * 16 + (kt >> 3) + c];
      *(uint4*)&Bs[n * 72 + c * 8] = v;
    }
    __syncthreads();
#pragma unroll
    for (int kk = 0; kk < 64; kk += 32) {
      v8s af[4], bf_[4];
#pragma unroll
      for (int i = 0; i < 4; ++i)
        af[i] = *(const v8s*)&As[(mb + i * 16 + qm) * 72 + kk + quad * 8];
#pragma unroll
      for (int j = 0; j < 4; ++j)
        bf_[j] = *(const v8s*)&Bs[(nb + j * 16 + qm) * 72 + kk + quad * 8];
#pragma unroll
      for (int i = 0; i < 4; ++i)
#pragma unroll
        for (int j = 0; j < 4; ++j)
          acc[i][j] = __builtin_amdgcn_mfma_f32_16x16x32_bf16(
              af[i], bf_[j], acc[i][j], 0, 0, 0);
    }
    __syncthreads();
  }
  // epilogue: D col = lane&15, row = quad*4 + reg (m89-verified)
  const int col_base = n0 + nb + qm;
  float bj[4];
#pragma unroll
  for (int j = 0; j < 4; ++j) bj[j] = bias[col_base + j * 16];
#pragma unroll
  for (int i = 0; i < 4; ++i) {
    int row = r0 + mb + i * 16 + quad * 4;
#pragma unroll
    for (int reg = 0; reg < 4; ++reg) {
      int rr = row + reg;
      if (rr < M) {
#pragma unroll
        for (int j = 0; j < 4; ++j)
          C[(size_t)rr * 256 + col_base + j * 16] = f2bf(acc[i][j][reg] + bj[j]);
      }
    }
  }
}

// ---------------------------------------------------------------------------
// GEMM2: out[M,47](f32) = A[M,256](bf16) @ W2(f32) + b2 ; 32 rows per block
// ---------------------------------------------------------------------------
__global__ __launch_bounds__(256) void k_gemm2(
    const unsigned short* __restrict__ A, const float* __restrict__ W2,
    const float* __restrict__ b2, float* __restrict__ out, int M) {
  __shared__ float Ws[256 * 47];
  __shared__ unsigned short As[32 * 264];
  const int t = threadIdx.x;
  for (int i = t; i < 256 * 47; i += 256) Ws[i] = W2[i];
  const int r0 = blockIdx.x * 32;
#pragma unroll
  for (int it = 0; it < 4; ++it) {
    int i = t + it * 256;          // 0..1023 ; 32 rows x 32 uint4
    int r = i >> 5, c = i & 31;
    uint4 v = make_uint4(0, 0, 0, 0);
    if (r0 + r < M) v = ((const uint4*)A)[(size_t)(r0 + r) * 32 + c];
    *(uint4*)&As[r * 264 + c * 8] = v;
  }
  __syncthreads();
  for (int o = t; o < 32 * 47; o += 256) {
    int r = o / 47, n = o - r * 47;
    if (r0 + r >= M) continue;
    float acc = b2[n];
#pragma unroll 8
    for (int k = 0; k < 256; ++k)
      acc = fmaf(bf2f(As[r * 264 + k]), Ws[k * 47 + n], acc);
    out[(size_t)(r0 + r) * 47 + n] = acc;
  }
}

// ---------------------------------------------------------------------------
// Launch
// ---------------------------------------------------------------------------
static inline size_t alignup(size_t x) { return (x + 255) & ~(size_t)255; }

extern "C" void kernel_launch(void* const* d_in, const int* in_sizes, int n_in,
                              void* d_out, int out_size, void* d_ws,
                              size_t ws_size, hipStream_t stream) {
  const float* features = (const float*)d_in[0];
  const int* s0   = (const int*)d_in[1];
  const int* s1   = (const int*)d_in[2];
  const int* s2   = (const int*)d_in[3];
  const int* src0 = (const int*)d_in[4];
  const int* dst0 = (const int*)d_in[5];
  const int* src1 = (const int*)d_in[6];
  const int* dst1 = (const int*)d_in[7];
  const float* W1 = (const float*)d_in[8];
  const float* b1 = (const float*)d_in[9];
  const float* W2 = (const float*)d_in[10];
  const float* b2 = (const float*)d_in[11];
  float* out = (float*)d_out;

  const int N0 = in_sizes[1], N1 = in_sizes[2];
  const int E0 = in_sizes[4], E1 = in_sizes[6];

  // ---- key derivation (partitionable; verified round 1) ----
  unsigned dk[3][2], kfs[3][2], khs[3][2];
  for (int i = 0; i < 3; ++i)
    threefry2x32(0u, 42u, 0u, (unsigned)i, dk[i][0], dk[i][1]);
  for (int i = 0; i < 3; ++i) {
    threefry2x32(dk[i][0], dk[i][1], 0u, 0u, kfs[i][0], kfs[i][1]);
    threefry2x32(dk[i][0], dk[i][1], 0u, 1u, khs[i][0], khs[i][1]);
  }

  // ---- workspace layout ----
  char* p = (char*)d_ws;
  auto take = [&](size_t bytes) {
    char* r = p;
    p += alignup(bytes);
    return r;
  };
  unsigned short* a1bf = (unsigned short*)take((size_t)N1 * 128 * 2);
  unsigned short* n1bf = (unsigned short*)take((size_t)N1 * 256 * 2);
  unsigned short* a0bf = (unsigned short*)take((size_t)N0 * 128 * 2);
  unsigned short* n0bf = (unsigned short*)take((size_t)N0 * 256 * 2);
  unsigned short* a2bf = (unsigned short*)take((size_t)N0 * 256 * 2);
  unsigned short* w1t  = (unsigned short*)take(256 * 128 * 2);
  int* off1  = (int*)take((size_t)(N1 + 2) * 4);
  int* deg1  = (int*)take((size_t)(N1 + 2) * 4);
  int* cur1  = (int*)take((size_t)N1 * 4);
  int* off0  = (int*)take((size_t)(N0 + 2) * 4);
  int* deg0  = (int*)take((size_t)(N0 + 2) * 4);
  int* cur0  = (int*)take((size_t)N0 * 4);
  int* bsum  = (int*)take(1024 * 4);
  int* bsumx = (int*)take(1024 * 4);
  int* dummy = (int*)take(1024 * 4);
  int* csr1_r = (int*)take((size_t)E1 * 4);
  int* csr1_g = (int*)take((size_t)E1 * 4);
  int* csr0_r = (int*)take((size_t)E0 * 4);
  int* csr0_g = (int*)take((size_t)E0 * 4);

  hipMemsetAsync(deg1, 0, (size_t)(N1 + 2) * 4, stream);
  hipMemsetAsync(deg0, 0, (size_t)(N0 + 2) * 4, stream);
  hipMemsetAsync(cur1, 0, (size_t)N1 * 4, stream);
  hipMemsetAsync(cur0, 0, (size_t)N0 * 4, stream);

  k_prepW<<<128, 256, 0, stream>>>(W1, w1t);
  k_count<<<(E1 + 255) / 256, 256, 0, stream>>>(dst1, deg1, E1);
  k_count<<<(E0 + 255) / 256, 256, 0, stream>>>(dst0, deg0, E0);

  // exclusive scans over N+1 entries (deg[N]=0 -> off[N]=E)
  {
    int n = N1 + 1, B = (n + 1023) / 1024;
    k_scan1<<<B, 256, 0, stream>>>(deg1, off1, bsum, n);
    k_scan1<<<1, 256, 0, stream>>>(bsum, bsumx, dummy, B);
    k_scan3<<<B, 256, 0, stream>>>(off1, bsumx, n);
  }
  {
    int n = N0 + 1, B = (n + 1023) / 1024;
    k_scan1<<<B, 256, 0, stream>>>(deg0, off0, bsum, n);
    k_scan1<<<1, 256, 0, stream>>>(bsum, bsumx, dummy, B);
    k_scan3<<<B, 256, 0, stream>>>(off0, bsumx, n);
  }

  k_fill<<<(E1 + 255) / 256, 256, 0, stream>>>(src1, dst1, s2, off1, cur1,
                                               csr1_r, csr1_g, E1);
  k_fill<<<(E0 + 255) / 256, 256, 0, stream>>>(src0, dst0, s1, off0, cur0,
                                               csr0_r, csr0_g, E0);

  // layer 0, hop 1: a1 = agg(graph1, h2, h1) ; n1 = a1@W1+b1
  k_agg128<<<(N1 + 3) / 4, 256, 0, stream>>>(
      features, off1, csr1_r, csr1_g, s1, a1bf, N1,
      kfs[1][0], kfs[1][1], khs[1][0], khs[1][1]);
  {
    dim3 g((N1 + 127) / 128, 2);
    k_gemm1<<<g, 256, 0, stream>>>(a1bf, w1t, b1, n1bf, N1);
  }

  // layer 0, hop 0: a0 = agg(graph0, h1, h0) ; n0 = a0@W1+b1
  k_agg128<<<(N0 + 3) / 4, 256, 0, stream>>>(
      features, off0, csr0_r, csr0_g, s0, a0bf, N0,
      kfs[0][0], kfs[0][1], khs[0][0], khs[0][1]);
  {
    dim3 g((N0 + 127) / 128, 2);
    k_gemm1<<<g, 256, 0, stream>>>(a0bf, w1t, b1, n0bf, N0);
  }

  // layer 1: a = agg(graph0, n1, n0) ; out = a@W2+b2
  k_agg256<<<(N0 + 3) / 4, 256, 0, stream>>>(
      n1bf, off0, csr0_r, n0bf, a2bf, N0,
      kfs[2][0], kfs[2][1], khs[2][0], khs[2][1]);
  k_gemm2<<<(N0 + 31) / 32, 256, 0, stream>>>(a2bf, W2, b2, out, N0);
}